// Round 4
// baseline (326.224 us; speedup 1.0000x reference)
//
#include <hip/hip_runtime.h>
#include <stdint.h>

// Problem: N=131072, D=128, W=16, R=5
//   logit[n,r] = e1[n]^T C_r e2[n],  C_r = sum_w weight[w,r] * M_w
//   out[0] = -mean(log_softmax(logit)[n, rels[n]]),  out[1..N] = expected rating
//
// R12: raise residency. R11 post-mortem: atomic removal changed nothing ->
//   per-block wall time ~29 us (70k cyc) vs ~6k cyc of countable work, all
//   pipes ~10%, occupancy 26%. Pure latency-hiding deficit: the (256,3)
//   launch bound (relic of the R6/R7 spill era) caps residency at 3
//   blocks/CU while the kernel now needs only 80 VGPR / 23.5 KB LDS --
//   both admit 6 blocks/CU. Single change: __launch_bounds__(256,6).
//   Spill tell: WRITE_SIZE (640KB clean); VGPR cap 512/6 = 85 >= 80 natural.

#define NTOT 131072
#define DDIM 128
#define WBAS 16
#define RCLS 5
#define BN   64
#define SA   144     // LDS row stride (bf16); 288 B rows: conflict-free b128
#define NBLK (NTOT / BN)

typedef __attribute__((ext_vector_type(8))) short bf16x8;
typedef __attribute__((ext_vector_type(4))) float f32x4;

__device__ __forceinline__ unsigned short f2bf(float x) {
    union { float f; unsigned u; } v; v.f = x;
    unsigned u = v.u + 0x7FFFu + ((v.u >> 16) & 1u);
    return (unsigned short)(u >> 16);
}

// ---- prep: coalesced read (lanes along e), LDS transpose, bf16 ----
// grid = 80 blocks: r = bx>>4 (5), d-band d0 = (bx&15)*8 (16)
__global__ __launch_bounds__(256) void prep_kernel(
    const float* __restrict__ rel_embeds,    // [W][d][e]
    const float* __restrict__ wsc,           // [W][R]
    unsigned short* __restrict__ Cth)        // [R][e][d] bf16
{
    __shared__ float tile[8][129];
    const int bx = blockIdx.x;
    const int r  = bx >> 4;
    const int d0 = (bx & 15) << 3;
    const int t  = threadIdx.x;

    const int e  = t & 127;     // lanes consecutive in e -> coalesced reads
    const int dl = t >> 7;      // 0..1

    float acc[4] = {0.f, 0.f, 0.f, 0.f};
    for (int w = 0; w < WBAS; ++w) {
        float s = wsc[w * RCLS + r];
#pragma unroll
        for (int dd = 0; dd < 4; ++dd)
            acc[dd] += s * rel_embeds[w * 16384 + (d0 + dd * 2 + dl) * 128 + e];
    }
#pragma unroll
    for (int dd = 0; dd < 4; ++dd) tile[dd * 2 + dl][e] = acc[dd];
    __syncthreads();

    if (t < 128) {          // thread t -> output column e=t, all 8 d of the band
        unsigned short h[8];
#pragma unroll
        for (int j = 0; j < 8; ++j) h[j] = f2bf(tile[j][t]);
        size_t base = (size_t)r * 16384 + (size_t)t * 128 + d0;   // 16B aligned
        *(ushort4*)(Cth + base)     = make_ushort4(h[0], h[1], h[2], h[3]);
        *(ushort4*)(Cth + base + 4) = make_ushort4(h[4], h[5], h[6], h[7]);
    }
}

// ---- main fused kernel: 4 waves; wave w = e-band [32w, 32w+32), all 64 rows ----
__global__ __launch_bounds__(256, 6) void bilinear_mfma_kernel(
    const float* __restrict__ e1g,           // [N, D]
    const float* __restrict__ e2g,           // [N, D]
    const unsigned short* __restrict__ Cth,  // [R, 128(e), 128(d)] bf16
    const int*   __restrict__ rels,
    float* __restrict__ out,                 // [1 + N]
    float* __restrict__ loss_ws,             // [NBLK] per-block loss partials
    float inv_n)
{
    __shared__ __align__(16) unsigned short s_hi[BN][SA];
    __shared__ float s_part[4][BN][RCLS];    // per-wave logit partials (no atomics)

    const int tid  = threadIdx.x;
    const int n0   = blockIdx.x * BN;
    const int lane = tid & 63;
    const int w    = tid >> 6;      // wave id -> e-band [32w, 32w+32)
    const int l15  = lane & 15;
    const int q    = lane >> 4;

    // e2 in (swapped) C-fragment layout: lane holds 4 consecutive e at fixed n.
    // e2r[et][nt][i] = e2[n0+16nt+l15][32w+16et+4q+i]  -> one float4 per (et,nt)
    f32x4 e2r[2][4];
#pragma unroll
    for (int nt = 0; nt < 4; ++nt) {
        const float* p = e2g + (size_t)(n0 + 16 * nt + l15) * DDIM + 32 * w + 4 * q;
        e2r[0][nt] = *(const f32x4*)p;
        e2r[1][nt] = *(const f32x4*)(p + 16);
    }

    // stage e1 -> bf16 in LDS (64 rows x 32 float4)
#pragma unroll
    for (int it = 0; it < 8; ++it) {
        int idx = it * 256 + tid;
        int row = idx >> 5, c4 = idx & 31;
        float4 v = ((const float4*)(e1g + (size_t)(n0 + row) * DDIM))[c4];
        *(ushort4*)&s_hi[row][c4 * 4] =
            make_ushort4(f2bf(v.x), f2bf(v.y), f2bf(v.z), f2bf(v.w));
    }
    __syncthreads();

    // A-fragment (Cth) offsets: rows e = 32w+16et+l15, k-slice d = 8q (+32*k4)
    const int aofs0 = (32 * w + l15) * DDIM + q * 8;   // et=0: e in [32w, 32w+16)
    const int aofs1 = aofs0 + 16 * DDIM;               // et=1: e in [32w+16, 32w+32)

    const unsigned short* ag = Cth;

#pragma unroll 1
    for (int r = 0; r < RCLS; ++r) {
        f32x4 acc[2][4];
#pragma unroll
        for (int et = 0; et < 2; ++et)
#pragma unroll
            for (int nt = 0; nt < 4; ++nt) {
                f32x4 z = {0.0f, 0.0f, 0.0f, 0.0f};
                acc[et][nt] = z;
            }

#pragma unroll
        for (int k4 = 0; k4 < 4; ++k4) {
            bf16x8 a0 = *(const bf16x8*)(ag + aofs0 + k4 * 32);
            bf16x8 a1 = *(const bf16x8*)(ag + aofs1 + k4 * 32);
            bf16x8 bh[4];
#pragma unroll
            for (int nt = 0; nt < 4; ++nt)
                bh[nt] = *(const bf16x8*)&s_hi[16 * nt + l15][k4 * 32 + q * 8];
#pragma unroll
            for (int nt = 0; nt < 4; ++nt) {
                acc[0][nt] = __builtin_amdgcn_mfma_f32_16x16x32_bf16(a0, bh[nt], acc[0][nt], 0, 0, 0);
                acc[1][nt] = __builtin_amdgcn_mfma_f32_16x16x32_bf16(a1, bh[nt], acc[1][nt], 0, 0, 0);
            }
        }

        // contract with e2: sum over (et,i) in-register, then over q (2 shfl),
        // store per-wave partial (rows 16nt+l15 for lanes 0..15)
#pragma unroll
        for (int nt = 0; nt < 4; ++nt) {
            f32x4 t = acc[0][nt] * e2r[0][nt] + acc[1][nt] * e2r[1][nt];
            float p = t[0] + t[1] + t[2] + t[3];
            p += __shfl_xor(p, 16);
            p += __shfl_xor(p, 32);
            if (lane < 16) s_part[w][16 * nt + lane][r] = p;
        }

        ag += 16384;
    }
    __syncthreads();

    // epilogue: one thread per row; sum the 4 per-wave band partials
    if (tid < BN) {
        float l[RCLS];
#pragma unroll
        for (int r = 0; r < RCLS; ++r)
            l[r] = s_part[0][tid][r] + s_part[1][tid][r]
                 + s_part[2][tid][r] + s_part[3][tid][r];
        float mx = l[0];
#pragma unroll
        for (int r = 1; r < RCLS; ++r) mx = fmaxf(mx, l[r]);
        float e[RCLS], se = 0.0f;
#pragma unroll
        for (int r = 0; r < RCLS; ++r) { e[r] = __expf(l[r] - mx); se += e[r]; }
        float inv_se = 1.0f / se;
        float pred = 0.0f;
#pragma unroll
        for (int r = 0; r < RCLS; ++r) pred += (float)(r + 1) * e[r] * inv_se;
        out[1 + n0 + tid] = pred;

        int rel = rels[n0 + tid];
        float lossc = -(l[rel] - mx - logf(se)) * inv_n;
#pragma unroll
        for (int m = 1; m <= 32; m <<= 1) lossc += __shfl_xor(lossc, m);
        if (lane == 0) loss_ws[blockIdx.x] = lossc;   // plain store, no atomic
    }
}

// ---- final: reduce the 2048 per-block partials into out[0] ----
__global__ __launch_bounds__(256) void loss_reduce_kernel(
    const float* __restrict__ loss_ws, float* __restrict__ out)
{
    __shared__ float s[4];
    float v = 0.0f;
    for (int i = threadIdx.x; i < NBLK; i += 256) v += loss_ws[i];
#pragma unroll
    for (int m = 1; m <= 32; m <<= 1) v += __shfl_xor(v, m);
    if ((threadIdx.x & 63) == 0) s[threadIdx.x >> 6] = v;
    __syncthreads();
    if (threadIdx.x == 0) out[0] = s[0] + s[1] + s[2] + s[3];
}

extern "C" void kernel_launch(void* const* d_in, const int* in_sizes, int n_in,
                              void* d_out, int out_size, void* d_ws, size_t ws_size,
                              hipStream_t stream) {
    const float* e1   = (const float*)d_in[0];
    const float* e2   = (const float*)d_in[1];
    const float* rele = (const float*)d_in[2];
    const float* wsc  = (const float*)d_in[3];
    const int*   rels = (const int*)d_in[4];
    float* out = (float*)d_out;

    unsigned short* Cth = (unsigned short*)d_ws;             // 163840 B
    float* loss_ws = (float*)((char*)d_ws + 163840);         // 8192 B

    prep_kernel<<<80, 256, 0, stream>>>(rele, wsc, Cth);
    bilinear_mfma_kernel<<<NBLK, 256, 0, stream>>>(
        e1, e2, Cth, rels, out, loss_ws, 1.0f / (float)NTOT);
    loss_reduce_kernel<<<1, 256, 0, stream>>>(loss_ws, out);
}

// Round 5
// 197.331 us; speedup vs baseline: 1.6532x; 1.6532x over previous
//
#include <hip/hip_runtime.h>
#include <stdint.h>

// Problem: N=131072, D=128, W=16, R=5
//   logit[n,r] = e1[n]^T C_r e2[n],  C_r = sum_w weight[w,r] * M_w
//   out[0] = -mean(log_softmax(logit)[n, rels[n]]),  out[1..N] = expected rating
//
// R13: persistent blocks + T14 async-STAGE pipeline.
//   R12 lesson: VGPR quantized at 64/128/256 (80 -> 128-slot, 16 waves/CU
//   hard cap) AND the memory system delivered 2.95 TB/s when given enough
//   requests -> R11 (890 GB/s) was request-starved, not BW-bound.
//   Fix occupancy-invariant overlap: grid=1024 persistent blocks x 2 groups,
//   double-buffered s_hi/s_part, ONE barrier per group:
//     - e2(g) issued at loop top, first use ~600cyc later (hidden, 0 extra regs)
//     - e1(g+1) prefetched in two 4-load halves (pf[4]=16 regs max):
//       issue A pre-r0 -> cvt+store after r1 -> issue B -> cvt+store after r3
//   Peak regs ~120-130 < 168 cap (256,3). LDS 47.1KB -> 3 blocks/CU.
//   Spill tell: WRITE_SIZE (640KB clean).

#define NTOT 131072
#define DDIM 128
#define WBAS 16
#define RCLS 5
#define BN   64
#define SA   144     // LDS row stride (bf16); 288 B rows: conflict-free b128
#define NG   (NTOT / BN)   // 2048 groups
#define GRID 1024          // 2 groups per persistent block

typedef __attribute__((ext_vector_type(8))) short bf16x8;
typedef __attribute__((ext_vector_type(4))) float f32x4;

__device__ __forceinline__ unsigned short f2bf(float x) {
    union { float f; unsigned u; } v; v.f = x;
    unsigned u = v.u + 0x7FFFu + ((v.u >> 16) & 1u);
    return (unsigned short)(u >> 16);
}

__device__ __forceinline__ ushort4 f2bf4(float4 v) {
    return make_ushort4(f2bf(v.x), f2bf(v.y), f2bf(v.z), f2bf(v.w));
}

// ---- prep: coalesced read (lanes along e), LDS transpose, bf16 ----
// grid = 80 blocks: r = bx>>4 (5), d-band d0 = (bx&15)*8 (16)
__global__ __launch_bounds__(256) void prep_kernel(
    const float* __restrict__ rel_embeds,    // [W][d][e]
    const float* __restrict__ wsc,           // [W][R]
    unsigned short* __restrict__ Cth)        // [R][e][d] bf16
{
    __shared__ float tile[8][129];
    const int bx = blockIdx.x;
    const int r  = bx >> 4;
    const int d0 = (bx & 15) << 3;
    const int t  = threadIdx.x;

    const int e  = t & 127;     // lanes consecutive in e -> coalesced reads
    const int dl = t >> 7;      // 0..1

    float acc[4] = {0.f, 0.f, 0.f, 0.f};
    for (int w = 0; w < WBAS; ++w) {
        float s = wsc[w * RCLS + r];
#pragma unroll
        for (int dd = 0; dd < 4; ++dd)
            acc[dd] += s * rel_embeds[w * 16384 + (d0 + dd * 2 + dl) * 128 + e];
    }
#pragma unroll
    for (int dd = 0; dd < 4; ++dd) tile[dd * 2 + dl][e] = acc[dd];
    __syncthreads();

    if (t < 128) {          // thread t -> output column e=t, all 8 d of the band
        unsigned short h[8];
#pragma unroll
        for (int j = 0; j < 8; ++j) h[j] = f2bf(tile[j][t]);
        size_t base = (size_t)r * 16384 + (size_t)t * 128 + d0;   // 16B aligned
        *(ushort4*)(Cth + base)     = make_ushort4(h[0], h[1], h[2], h[3]);
        *(ushort4*)(Cth + base + 4) = make_ushort4(h[4], h[5], h[6], h[7]);
    }
}

// ---- main fused kernel: persistent, 4 waves; wave w = e-band [32w,32w+32) ----
__global__ __launch_bounds__(256, 3) void bilinear_mfma_kernel(
    const float* __restrict__ e1g,           // [N, D]
    const float* __restrict__ e2g,           // [N, D]
    const unsigned short* __restrict__ Cth,  // [R, 128(e), 128(d)] bf16
    const int*   __restrict__ rels,
    float* __restrict__ out,                 // [1 + N]
    float* __restrict__ loss_ws,             // [NG] per-group loss partials
    float inv_n)
{
    __shared__ __align__(16) unsigned short s_hi[2][BN][SA];
    __shared__ float s_part[2][4][BN][RCLS];

    const int tid  = threadIdx.x;
    const int lane = tid & 63;
    const int w    = tid >> 6;      // wave id -> e-band [32w, 32w+32)
    const int l15  = lane & 15;
    const int q    = lane >> 4;
    const int sr0  = tid >> 5;      // staging: row offset within 8-row slab
    const int sc4  = tid & 31;      // staging: float4 column

    const int bofs  = l15 * SA + q * 8;                 // bh read base (shorts)
    const int aofs0 = (32 * w + l15) * DDIM + q * 8;    // Cth rows e in [32w,32w+16)
    const int aofs1 = aofs0 + 16 * DDIM;                // e in [32w+16, 32w+32)

    int g = blockIdx.x;
    int b = 0;

    // prologue: stage group g into buffer 0 (nothing to hide behind)
    {
        const float* e1b = e1g + (size_t)g * BN * DDIM;
        float4 v[8];
#pragma unroll
        for (int it = 0; it < 8; ++it)
            v[it] = *(const float4*)(e1b + (it * 8 + sr0) * DDIM + sc4 * 4);
#pragma unroll
        for (int it = 0; it < 8; ++it)
            *(ushort4*)&s_hi[0][it * 8 + sr0][sc4 * 4] = f2bf4(v[it]);
    }
    __syncthreads();

    for (; g < NG; g += GRID) {
        const int n0 = g * BN;
        const int gn = g + GRID;
        const float* e1n = e1g + (size_t)gn * BN * DDIM;   // deref'd only if gn<NG
        const unsigned short* sb = &s_hi[b][0][0];
        unsigned short*       sn = &s_hi[b ^ 1][0][0];

        // e2 for current group: issue first (oldest in vmcnt queue),
        // first consumed after r=0's MFMA block (~600 cyc of cover)
        f32x4 e2r[2][4];
#pragma unroll
        for (int nt = 0; nt < 4; ++nt) {
            const float* pp = e2g + (size_t)(n0 + 16 * nt + l15) * DDIM + 32 * w + 4 * q;
            e2r[0][nt] = *(const f32x4*)pp;
            e2r[1][nt] = *(const f32x4*)(pp + 16);
        }

        // prefetch half A of next group's e1 (16 regs)
        float4 pf[4];
        if (gn < NG) {
#pragma unroll
            for (int it = 0; it < 4; ++it)
                pf[it] = *(const float4*)(e1n + (it * 8 + sr0) * DDIM + sc4 * 4);
        }

        const unsigned short* ag = Cth;
#pragma unroll 1
        for (int r = 0; r < RCLS; ++r) {
            f32x4 acc[2][4];
#pragma unroll
            for (int et = 0; et < 2; ++et)
#pragma unroll
                for (int nt = 0; nt < 4; ++nt) {
                    f32x4 z = {0.0f, 0.0f, 0.0f, 0.0f};
                    acc[et][nt] = z;
                }

#pragma unroll
            for (int k4 = 0; k4 < 4; ++k4) {
                bf16x8 a0 = *(const bf16x8*)(ag + aofs0 + k4 * 32);
                bf16x8 a1 = *(const bf16x8*)(ag + aofs1 + k4 * 32);
                bf16x8 bh[4];
#pragma unroll
                for (int nt = 0; nt < 4; ++nt)
                    bh[nt] = *(const bf16x8*)(sb + bofs + nt * (16 * SA) + k4 * 32);
#pragma unroll
                for (int nt = 0; nt < 4; ++nt) {
                    acc[0][nt] = __builtin_amdgcn_mfma_f32_16x16x32_bf16(a0, bh[nt], acc[0][nt], 0, 0, 0);
                    acc[1][nt] = __builtin_amdgcn_mfma_f32_16x16x32_bf16(a1, bh[nt], acc[1][nt], 0, 0, 0);
                }
            }

            // contract with e2; reduce over q via 2 shfl; per-wave partial
#pragma unroll
            for (int nt = 0; nt < 4; ++nt) {
                f32x4 t = acc[0][nt] * e2r[0][nt] + acc[1][nt] * e2r[1][nt];
                float p2 = t[0] + t[1] + t[2] + t[3];
                p2 += __shfl_xor(p2, 16);
                p2 += __shfl_xor(p2, 32);
                if (lane < 16) s_part[b][w][16 * nt + lane][r] = p2;
            }

            // async-STAGE: cvt+store half A after r1 (frees pf), issue half B;
            // cvt+store half B after r3. Writes go to the OTHER buffer.
            if (r == 1 && gn < NG) {
#pragma unroll
                for (int it = 0; it < 4; ++it)
                    *(ushort4*)(sn + (it * 8 + sr0) * SA + sc4 * 4) = f2bf4(pf[it]);
#pragma unroll
                for (int it = 0; it < 4; ++it)
                    pf[it] = *(const float4*)(e1n + ((it + 4) * 8 + sr0) * DDIM + sc4 * 4);
            } else if (r == 3 && gn < NG) {
#pragma unroll
                for (int it = 0; it < 4; ++it)
                    *(ushort4*)(sn + ((it + 4) * 8 + sr0) * SA + sc4 * 4) = f2bf4(pf[it]);
            }

            ag += 16384;
        }
        __syncthreads();   // s_hi[b^1] staged, s_part[b] complete

        // epilogue for group g: one thread per row; other waves proceed
        // (they write s_part[b^1] / s_hi[b] only after this barrier -> no race)
        if (tid < BN) {
            float l[RCLS];
#pragma unroll
            for (int r = 0; r < RCLS; ++r)
                l[r] = s_part[b][0][tid][r] + s_part[b][1][tid][r]
                     + s_part[b][2][tid][r] + s_part[b][3][tid][r];
            float mx = l[0];
#pragma unroll
            for (int r = 1; r < RCLS; ++r) mx = fmaxf(mx, l[r]);
            float e[RCLS], se = 0.0f;
#pragma unroll
            for (int r = 0; r < RCLS; ++r) { e[r] = __expf(l[r] - mx); se += e[r]; }
            float inv_se = 1.0f / se;
            float pred = 0.0f;
#pragma unroll
            for (int r = 0; r < RCLS; ++r) pred += (float)(r + 1) * e[r] * inv_se;
            out[1 + n0 + tid] = pred;

            int rel = rels[n0 + tid];
            float lossc = -(l[rel] - mx - logf(se)) * inv_n;
#pragma unroll
            for (int m = 1; m <= 32; m <<= 1) lossc += __shfl_xor(lossc, m);
            if (lane == 0) loss_ws[g] = lossc;   // plain store, no atomic
        }
        b ^= 1;
    }
}

// ---- final: reduce the per-group partials into out[0] ----
__global__ __launch_bounds__(256) void loss_reduce_kernel(
    const float* __restrict__ loss_ws, float* __restrict__ out)
{
    __shared__ float s[4];
    float v = 0.0f;
    for (int i = threadIdx.x; i < NG; i += 256) v += loss_ws[i];
#pragma unroll
    for (int m = 1; m <= 32; m <<= 1) v += __shfl_xor(v, m);
    if ((threadIdx.x & 63) == 0) s[threadIdx.x >> 6] = v;
    __syncthreads();
    if (threadIdx.x == 0) out[0] = s[0] + s[1] + s[2] + s[3];
}

extern "C" void kernel_launch(void* const* d_in, const int* in_sizes, int n_in,
                              void* d_out, int out_size, void* d_ws, size_t ws_size,
                              hipStream_t stream) {
    const float* e1   = (const float*)d_in[0];
    const float* e2   = (const float*)d_in[1];
    const float* rele = (const float*)d_in[2];
    const float* wsc  = (const float*)d_in[3];
    const int*   rels = (const int*)d_in[4];
    float* out = (float*)d_out;

    unsigned short* Cth = (unsigned short*)d_ws;             // 163840 B
    float* loss_ws = (float*)((char*)d_ws + 163840);         // 8192 B

    prep_kernel<<<80, 256, 0, stream>>>(rele, wsc, Cth);
    bilinear_mfma_kernel<<<GRID, 256, 0, stream>>>(
        e1, e2, Cth, rels, out, loss_ws, 1.0f / (float)NTOT);
    loss_reduce_kernel<<<1, 256, 0, stream>>>(loss_ws, out);
}

// Round 6
// 180.600 us; speedup vs baseline: 1.8063x; 1.0926x over previous
//
#include <hip/hip_runtime.h>
#include <stdint.h>

// Problem: N=131072, D=128, W=16, R=5
//   logit[n,r] = e1[n]^T C_r e2[n],  C_r = sum_w weight[w,r] * M_w
//   out[0] = -mean(log_softmax(logit)[n, rels[n]]),  out[1..N] = expected rating
//
// R14: pin Cth A-fragments in registers (grid-constant!), 512-thread blocks.
//   R12/R13 bracket: occupancy is pinned at 16 waves/CU by the 128-VGPR
//   quantization slot; below that we spill, above structure we starve. So
//   spend registers to 256 (same occupancy slot >128) and DELETE the
//   steady-state load chains:
//   - wave w owns e-band [16w,16w+16): its A-frags for all 5 r = 20 bf16x8
//     = 80 VGPR, loaded ONCE per kernel (Cth is constant across groups).
//   - bh (e1 frags) hoisted per-group into 64 VGPR (R10 retry: cap is now
//     256, not 168 -> no rematerialization pressure).
//   - persistent: grid=256, 8 contiguous groups/block, dbuf s_hi/s_part,
//     e1(g+1) prefetched into regs during r-loop, staged between r3/r4.
//   Steady state per group per wave: 8 VMEM + 16 ds_read + 80 MFMA + 40 shfl.
//   Tells: VGPR_Count ~190-240 (pin worked); WRITE_SIZE 640KB (no spill).

#define NTOT 131072
#define DDIM 128
#define WBAS 16
#define RCLS 5
#define BN   64
#define SA   144     // LDS row stride (bf16); 288 B rows: conflict-free b128
#define NG   (NTOT / BN)   // 2048 groups
#define GRID 256
#define GPB  (NG / GRID)   // 8 groups per block

typedef __attribute__((ext_vector_type(8))) short bf16x8;
typedef __attribute__((ext_vector_type(4))) float f32x4;

__device__ __forceinline__ unsigned short f2bf(float x) {
    union { float f; unsigned u; } v; v.f = x;
    unsigned u = v.u + 0x7FFFu + ((v.u >> 16) & 1u);
    return (unsigned short)(u >> 16);
}

__device__ __forceinline__ ushort4 f2bf4(float4 v) {
    return make_ushort4(f2bf(v.x), f2bf(v.y), f2bf(v.z), f2bf(v.w));
}

// ---- prep: coalesced read (lanes along e), LDS transpose, bf16 ----
// grid = 80 blocks: r = bx>>4 (5), d-band d0 = (bx&15)*8 (16)
__global__ __launch_bounds__(256) void prep_kernel(
    const float* __restrict__ rel_embeds,    // [W][d][e]
    const float* __restrict__ wsc,           // [W][R]
    unsigned short* __restrict__ Cth)        // [R][e][d] bf16
{
    __shared__ float tile[8][129];
    const int bx = blockIdx.x;
    const int r  = bx >> 4;
    const int d0 = (bx & 15) << 3;
    const int t  = threadIdx.x;

    const int e  = t & 127;     // lanes consecutive in e -> coalesced reads
    const int dl = t >> 7;      // 0..1

    float acc[4] = {0.f, 0.f, 0.f, 0.f};
    for (int w = 0; w < WBAS; ++w) {
        float s = wsc[w * RCLS + r];
#pragma unroll
        for (int dd = 0; dd < 4; ++dd)
            acc[dd] += s * rel_embeds[w * 16384 + (d0 + dd * 2 + dl) * 128 + e];
    }
#pragma unroll
    for (int dd = 0; dd < 4; ++dd) tile[dd * 2 + dl][e] = acc[dd];
    __syncthreads();

    if (t < 128) {          // thread t -> output column e=t, all 8 d of the band
        unsigned short h[8];
#pragma unroll
        for (int j = 0; j < 8; ++j) h[j] = f2bf(tile[j][t]);
        size_t base = (size_t)r * 16384 + (size_t)t * 128 + d0;   // 16B aligned
        *(ushort4*)(Cth + base)     = make_ushort4(h[0], h[1], h[2], h[3]);
        *(ushort4*)(Cth + base + 4) = make_ushort4(h[4], h[5], h[6], h[7]);
    }
}

// One r-step: 16 MFMA from pinned regs + contract + per-wave partial store.
// Macro so rr is a literal -> all array indexing compile-time (rule #20).
#define RSTEP(rr) do {                                                        \
    f32x4 acc0 = {0.f,0.f,0.f,0.f}, acc1 = {0.f,0.f,0.f,0.f};                 \
    f32x4 acc2 = {0.f,0.f,0.f,0.f}, acc3 = {0.f,0.f,0.f,0.f};                 \
    _Pragma("unroll")                                                         \
    for (int k4 = 0; k4 < 4; ++k4) {                                          \
        acc0 = __builtin_amdgcn_mfma_f32_16x16x32_bf16(a[rr][k4], bh[k4][0], acc0, 0, 0, 0); \
        acc1 = __builtin_amdgcn_mfma_f32_16x16x32_bf16(a[rr][k4], bh[k4][1], acc1, 0, 0, 0); \
        acc2 = __builtin_amdgcn_mfma_f32_16x16x32_bf16(a[rr][k4], bh[k4][2], acc2, 0, 0, 0); \
        acc3 = __builtin_amdgcn_mfma_f32_16x16x32_bf16(a[rr][k4], bh[k4][3], acc3, 0, 0, 0); \
    }                                                                         \
    _Pragma("unroll")                                                         \
    for (int nt = 0; nt < 4; ++nt) {                                          \
        f32x4 av = (nt==0)?acc0:((nt==1)?acc1:((nt==2)?acc2:acc3));           \
        f32x4 t = av * e2r[nt];                                               \
        float p = t[0] + t[1] + t[2] + t[3];                                  \
        p += __shfl_xor(p, 16);                                               \
        p += __shfl_xor(p, 32);                                               \
        if (lane < 16) s_part[b][w][16 * nt + lane][rr] = p;                  \
    }                                                                         \
} while (0)

// ---- main fused kernel: persistent, 8 waves; wave w = e-band [16w,16w+16) ----
__global__ __launch_bounds__(512, 2) void bilinear_mfma_kernel(
    const float* __restrict__ e1g,           // [N, D]
    const float* __restrict__ e2g,           // [N, D]
    const unsigned short* __restrict__ Cth,  // [R, 128(e), 128(d)] bf16
    const int*   __restrict__ rels,
    float* __restrict__ out,                 // [1 + N]
    float* __restrict__ loss_ws,             // [NG] per-group loss partials
    float inv_n)
{
    __shared__ __align__(16) unsigned short s_hi[2][BN][SA];
    __shared__ float s_part[2][8][BN][RCLS];

    const int tid  = threadIdx.x;            // 0..511
    const int lane = tid & 63;
    const int w    = tid >> 6;               // wave id 0..7 -> e-band [16w,16w+16)
    const int l15  = lane & 15;
    const int q    = lane >> 4;

    // Pin A-fragments: a[r][k4] = Cth[r][e=16w+l15][d=k4*32+q*8 ..+8]
    // 20 x bf16x8 = 80 VGPR, loaded once, live for the whole kernel.
    bf16x8 a[RCLS][4];
    {
        const unsigned short* ab = Cth + (16 * w + l15) * DDIM + q * 8;
#pragma unroll
        for (int r = 0; r < RCLS; ++r)
#pragma unroll
            for (int k4 = 0; k4 < 4; ++k4)
                a[r][k4] = *(const bf16x8*)(ab + r * 16384 + k4 * 32);
    }

    const int g0 = blockIdx.x * GPB;

    // prologue: stage e1(g0) into buffer 0 (512 threads x 4 float4)
    {
        const float* e1b = e1g + (size_t)g0 * BN * DDIM;
        float4 v[4];
#pragma unroll
        for (int it = 0; it < 4; ++it) {
            int idx = it * 512 + tid;
            v[it] = *(const float4*)(e1b + (idx >> 5) * DDIM + (idx & 31) * 4);
        }
#pragma unroll
        for (int it = 0; it < 4; ++it) {
            int idx = it * 512 + tid;
            *(ushort4*)&s_hi[0][idx >> 5][(idx & 31) * 4] = f2bf4(v[it]);
        }
    }
    __syncthreads();

    int b = 0;
#pragma unroll 1
    for (int gi = 0; gi < GPB; ++gi) {
        const int g  = g0 + gi;
        const int n0 = g * BN;

        // e2 fragments: e2r[nt][i] = e2[n0+16nt+l15][16w+4q+i] (one f32x4 each)
        f32x4 e2r[4];
#pragma unroll
        for (int nt = 0; nt < 4; ++nt)
            e2r[nt] = *(const f32x4*)(e2g + (size_t)(n0 + 16 * nt + l15) * DDIM
                                      + 16 * w + 4 * q);

        // bh fragments from s_hi[b], ONCE per group (r-independent): 64 VGPR
        bf16x8 bh[4][4];   // [k4][nt]
#pragma unroll
        for (int k4 = 0; k4 < 4; ++k4)
#pragma unroll
            for (int nt = 0; nt < 4; ++nt)
                bh[k4][nt] = *(const bf16x8*)&s_hi[b][16 * nt + l15][k4 * 32 + q * 8];

        // prefetch next group's e1 into regs (staged to LDS between r3/r4)
        float4 pf[4];
        if (gi + 1 < GPB) {
            const float* e1n = e1g + (size_t)(g + 1) * BN * DDIM;
#pragma unroll
            for (int it = 0; it < 4; ++it) {
                int idx = it * 512 + tid;
                pf[it] = *(const float4*)(e1n + (idx >> 5) * DDIM + (idx & 31) * 4);
            }
        }

        RSTEP(0);
        RSTEP(1);
        RSTEP(2);
        RSTEP(3);

        if (gi + 1 < GPB) {
#pragma unroll
            for (int it = 0; it < 4; ++it) {
                int idx = it * 512 + tid;
                *(ushort4*)&s_hi[b ^ 1][idx >> 5][(idx & 31) * 4] = f2bf4(pf[it]);
            }
        }

        RSTEP(4);
        __syncthreads();   // s_part[b] complete, s_hi[b^1] staged

        // epilogue for group g: wave 0, one thread per row; other waves roll on
        // (they touch only s_part[b^1] / s_hi[b^1]-reads / s_hi[b]-writes next)
        if (tid < BN) {
            float l[RCLS];
#pragma unroll
            for (int r = 0; r < RCLS; ++r) {
                float s = 0.f;
#pragma unroll
                for (int ww = 0; ww < 8; ++ww) s += s_part[b][ww][tid][r];
                l[r] = s;
            }
            float mx = l[0];
#pragma unroll
            for (int r = 1; r < RCLS; ++r) mx = fmaxf(mx, l[r]);
            float e[RCLS], se = 0.0f;
#pragma unroll
            for (int r = 0; r < RCLS; ++r) { e[r] = __expf(l[r] - mx); se += e[r]; }
            float inv_se = 1.0f / se;
            float pred = 0.0f;
#pragma unroll
            for (int r = 0; r < RCLS; ++r) pred += (float)(r + 1) * e[r] * inv_se;
            out[1 + n0 + tid] = pred;

            int rel = rels[n0 + tid];
            float lossc = -(l[rel] - mx - logf(se)) * inv_n;
#pragma unroll
            for (int m = 1; m <= 32; m <<= 1) lossc += __shfl_xor(lossc, m);
            if (lane == 0) loss_ws[g] = lossc;   // plain store, no atomic
        }
        b ^= 1;
    }
}

// ---- final: reduce the per-group partials into out[0] ----
__global__ __launch_bounds__(256) void loss_reduce_kernel(
    const float* __restrict__ loss_ws, float* __restrict__ out)
{
    __shared__ float s[4];
    float v = 0.0f;
    for (int i = threadIdx.x; i < NG; i += 256) v += loss_ws[i];
#pragma unroll
    for (int m = 1; m <= 32; m <<= 1) v += __shfl_xor(v, m);
    if ((threadIdx.x & 63) == 0) s[threadIdx.x >> 6] = v;
    __syncthreads();
    if (threadIdx.x == 0) out[0] = s[0] + s[1] + s[2] + s[3];
}

extern "C" void kernel_launch(void* const* d_in, const int* in_sizes, int n_in,
                              void* d_out, int out_size, void* d_ws, size_t ws_size,
                              hipStream_t stream) {
    const float* e1   = (const float*)d_in[0];
    const float* e2   = (const float*)d_in[1];
    const float* rele = (const float*)d_in[2];
    const float* wsc  = (const float*)d_in[3];
    const int*   rels = (const int*)d_in[4];
    float* out = (float*)d_out;

    unsigned short* Cth = (unsigned short*)d_ws;             // 163840 B
    float* loss_ws = (float*)((char*)d_ws + 163840);         // 8192 B

    prep_kernel<<<80, 256, 0, stream>>>(rele, wsc, Cth);
    bilinear_mfma_kernel<<<GRID, 512, 0, stream>>>(
        e1, e2, Cth, rels, out, loss_ws, 1.0f / (float)NTOT);
    loss_reduce_kernel<<<1, 256, 0, stream>>>(loss_ws, out);
}